// Round 7
// baseline (18.986 us; speedup 1.0000x reference)
//
#include <hip/hip_runtime.h>

#define DEV __device__ __forceinline__

namespace {

typedef float f32x2 __attribute__((ext_vector_type(2)));

DEV f32x2 splat(float x){ f32x2 r; r.x = x; r.y = x; return r; }
DEV f32x2 csw(f32x2 a){ return __builtin_shufflevector(a, a, 1, 0); }
DEV f32x2 cmulv(f32x2 a, f32x2 b){
  f32x2 nt; nt.x = -b.y; nt.y = b.x;
  return splat(a.x)*b + splat(a.y)*nt;
}
// a * e^{i phi} with cv=(c,c), sv=(-s,s)
DEV f32x2 cphase(f32x2 a, f32x2 cv, f32x2 sv){ return cv*a + sv*csw(a); }
DEV void halfsc(float th, float& c, float& s){ __sincosf(0.5f*th, &s, &c); }

constexpr float RSQRT2 = 0.70710678118654752440f;
constexpr float PI_F   = 3.14159265358979323846f;

// ---- cross-lane xor exchange, all within aligned 32-lane groups -----------
template<int CTRL> DEV float qperm(float v){
  return __int_as_float(__builtin_amdgcn_mov_dpp(__float_as_int(v), CTRL, 0xF, 0xF, true));
}
template<int OFF> DEV float swzf(float v){
  return __int_as_float(__builtin_amdgcn_ds_swizzle(__float_as_int(v), OFF));
}
template<int B> DEV float shfx(float v){
  if constexpr (B==1)      return qperm<0xB1>(v);      // quad_perm [1,0,3,2]
  else if constexpr (B==2) return qperm<0x4E>(v);      // quad_perm [2,3,0,1]
  else if constexpr (B==4) return swzf<0x101F>(v);     // xor 4
  else if constexpr (B==8) return qperm<0x128>(v);     // row_ror:8 == xor 8
  else                     return swzf<0x401F>(v);     // xor 16
}

// ---- fused 1-qubit encoding chain: H; then RZ/RX alternating (packed) -----
template<int NA> DEV void build_psi(f32x2 (&v)[2], const float* ang, float scale){
  v[0].x = RSQRT2; v[0].y = 0.f;
  v[1].x = RSQRT2; v[1].y = 0.f;
  #pragma unroll
  for (int i = 0; i < NA; ++i){
    float c, s; halfsc(scale * ang[i], c, s);
    f32x2 cv = splat(c);
    f32x2 sp; sp.x = s;  sp.y = -s;
    if ((i & 1) == 0){                     // RZ
      f32x2 sn; sn.x = -s; sn.y = s;
      v[0] = cv*v[0] + sp*csw(v[0]);
      v[1] = cv*v[1] + sn*csw(v[1]);
    } else {                               // RX
      f32x2 t0 = csw(v[0]), t1 = csw(v[1]);
      v[0] = cv*v[0] + sp*t1;
      v[1] = cv*v[1] + sp*t0;
    }
  }
}

// ---- gates on TWO 8-amp states (shared angles, interleaved for ILP) -------
template<int S> DEV void ry_loc8_2(f32x2 (&a)[2][8], float2 cs){
  const float c = cs.x, s = cs.y;
  #pragma unroll
  for (int m = 0; m < 8; ++m) if (!(m & S)) {
    #pragma unroll
    for (int st = 0; st < 2; ++st){
      f32x2 u = a[st][m], v = a[st][m|S];
      a[st][m]   = splat(c)*u - splat(s)*v;
      a[st][m|S] = splat(s)*u + splat(c)*v;
    }
  }
}
template<int MASK> DEV void ry_lane8_2(f32x2 (&a)[2][8], int r, float2 cs){
  const float c = cs.x;
  const float sg = (r & MASK) ? cs.y : -cs.y;
  #pragma unroll
  for (int m = 0; m < 8; ++m){
    #pragma unroll
    for (int st = 0; st < 2; ++st){
      f32x2 o; o.x = shfx<MASK>(a[st][m].x); o.y = shfx<MASK>(a[st][m].y);
      a[st][m] = splat(c)*a[st][m] + splat(sg)*o;
    }
  }
}

DEV f32x2 tov(float2 v){ f32x2 r; r.x = v.x; r.y = v.y; return r; }

} // namespace

// 16 samples per 256-thread block: 8 groups of 32 lanes, 2 samples per group
__global__ __launch_bounds__(256, 2)
void qnn_fused_kernel(const float* __restrict__ X,  const float* __restrict__ w1,
                      const float* __restrict__ w2, const float* __restrict__ fcw,
                      const float* __restrict__ fcb, float* __restrict__ out, int bs)
{
  __shared__ float4 Xlds4[16*49];           // 16 samples x 196 floats
  __shared__ float  feats[16][80];          // [64..79] zero pad for chain 7
  __shared__ float4 p1chain[16][16][5];     // phase-1 chains, row pad 5
  __shared__ float4 chain2[16][9];          // phase-2 chains, pad 9
  __shared__ float4 p1phi[2][2][8];         // {c,c,-s,s} per (l,Lb,m)
  __shared__ float2 p1ry[2][4];             // phase-1 RY (c,s) half-angle
  __shared__ float2 ryw[3][8];              // phase-2 RY (c,s) half-angle
  __shared__ float4 phi2[3*32*9];           // {c,c,-s,s}, row pad 9

  const int t  = threadIdx.x;
  const int g  = t >> 5;                    // group 0..7
  const int r  = t & 31;                    // lane id within group
  int sA = blockIdx.x * 16 + 2*g;
  int sB = sA + 1;
  if (sA >= bs) sA = bs - 1;
  if (sB >= bs) sB = bs - 1;

  // ---------------- stage X + weight tables --------------------------------
  {
    const float4* X4 = (const float4*)X;
    for (int idx = t; idx < 16*49; idx += 256){
      int s_ = idx / 49, e = idx - s_*49;
      int gs = blockIdx.x * 16 + s_;
      if (gs >= bs) gs = bs - 1;
      Xlds4[idx] = X4[(size_t)gs*49 + e];
    }
  }
  if (t < 32){                              // p1phi: l=t>>4, Lb=(t>>3)&1, m=t&7
    const int l = t >> 4, Lb = (t >> 3) & 1, m = t & 7;
    const float h0 = 0.5f*w1[l*8+0], h1 = 0.5f*w1[l*8+1];
    const float h2 = 0.5f*w1[l*8+2], h3 = 0.5f*w1[l*8+3];
    const bool m4 = m & 4, m2 = m & 2, m1 = m & 1;
    float phi = 0.f;
    phi += Lb ? (m4 ? h0 : -h0) : 0.f;      // CRZ(w0,w1)
    phi += m4 ? (m2 ? h1 : -h1) : 0.f;      // CRZ(w1,w2)
    phi += m2 ? (m1 ? h2 : -h2) : 0.f;      // CRZ(w2,w3)
    phi += m1 ? (Lb ? h3 : -h3) : 0.f;      // CRZ(w3,w0)
    float c, s; __sincosf(phi, &s, &c);
    p1phi[l][Lb][m] = {c, c, -s, s};
  } else if (t < 40){
    const int j = t - 32, l = j >> 2, i = j & 3;
    float c, s; halfsc(w1[l*8 + 4 + i], c, s); p1ry[l][i] = {c, s};
  } else if (t < 64){
    const int j = t - 40, l = j >> 3, i = j & 7;
    float c, s; halfsc(w2[l*16 + 8 + i], c, s); ryw[l][i] = {c, s};
  }
  for (int idx = t; idx < 3*256; idx += 256){
    const int l = idx >> 8, rr = (idx >> 3) & 31, mm = idx & 7;
    const float* wl = w2 + l*16;
    const float h0 = 0.5f*wl[0], h1 = 0.5f*wl[1], h2 = 0.5f*wl[2], h3 = 0.5f*wl[3];
    const float h4 = 0.5f*wl[4], h5 = 0.5f*wl[5], h6 = 0.5f*wl[6], h7 = 0.5f*wl[7];
    const bool b16 = rr & 16, b8 = rr & 8, b4 = rr & 4, b2 = rr & 2, b1 = rr & 1;
    const bool m4 = mm & 4, m2 = mm & 2, m1 = mm & 1;
    float phi = 0.f;
    phi += b16 ? (b8 ? h0 : -h0) : 0.f;     // (w0,w1)
    phi += b8  ? (b4 ? h1 : -h1) : 0.f;     // (w1,w2)
    phi += b4  ? (b2 ? h2 : -h2) : 0.f;     // (w2,w3)
    phi += b2  ? (b1 ? h3 : -h3) : 0.f;     // (w3,w4)
    phi += b1  ? (m4 ? h4 : -h4) : 0.f;     // (w4,w5)
    phi += m4  ? (m2 ? h5 : -h5) : 0.f;     // (w5,w6)
    phi += m2  ? (m1 ? h6 : -h6) : 0.f;     // (w6,w7)
    phi += m1  ? (b16 ? h7 : -h7) : 0.f;    // (w7,w0)
    float c, s; __sincosf(phi, &s, &c);
    phi2[(l*32 + rr)*9 + mm] = {c, c, -s, s};
  }
  __syncthreads();

  // ------ phase-1 chains: 1024 jobs (sample,patch,wire), 4 per thread ------
  #pragma unroll
  for (int jj = 0; jj < 4; ++jj){
    const int j = t + jj*256;
    const int s_ = j >> 6, p = (j >> 2) & 15, q = j & 3;
    const int pi = p >> 2, pj = p & 3;
    const int shift = (pj == 3) ? 1 : 2;
    const int cmask = (1 << shift) - 1;
    const int limit = ((pi == 3) ? 2 : 4) << shift;
    const float* Xf = (const float*)Xlds4 + s_*196;
    float ang[4];
    #pragma unroll
    for (int i = 0; i < 4; ++i){
      const int k = q*4 + i;
      int idx = (pi*4 + (k >> shift))*14 + pj*4 + (k & cmask);
      idx = idx > 195 ? 195 : idx;
      float v = Xf[idx];
      ang[i] = (k < limit) ? v : 0.f;       // RZ(0)/RX(0) == identity
    }
    f32x2 v[2];
    build_psi<4>(v, ang, 1.0f);
    p1chain[s_][p][q] = {v[0].x, v[0].y, v[1].x, v[1].y};
  }
  __syncthreads();

  // ------ phase 1 evolution: patch p=r>>1, wire0 = lane bit, 2 samples -----
  {
    const int p = r >> 1, Lb = r & 1;
    f32x2 a8[2][8];
    #pragma unroll
    for (int st = 0; st < 2; ++st){
      f32x2 ps[4][2];
      #pragma unroll
      for (int q = 0; q < 4; ++q){
        float4 fq = p1chain[2*g + st][p][q];
        ps[q][0].x = fq.x; ps[q][0].y = fq.y;
        ps[q][1].x = fq.z; ps[q][1].y = fq.w;
      }
      f32x2 t12[4];
      #pragma unroll
      for (int j = 0; j < 4; ++j) t12[j] = cmulv(ps[1][j>>1], ps[2][j&1]);
      f32x2 base = Lb ? ps[0][1] : ps[0][0];
      f32x2 bt[4];
      #pragma unroll
      for (int j = 0; j < 4; ++j) bt[j] = cmulv(base, t12[j]);
      #pragma unroll
      for (int m = 0; m < 8; ++m) a8[st][m] = cmulv(bt[m>>1], ps[3][m&1]);
    }

    #pragma unroll
    for (int l = 0; l < 2; ++l){
      const float4* ph = &p1phi[l][Lb][0];
      #pragma unroll
      for (int m = 0; m < 8; ++m){
        float4 w = ph[m];
        f32x2 cv; cv.x = w.x; cv.y = w.y;
        f32x2 sv; sv.x = w.z; sv.y = w.w;
        a8[0][m] = cphase(a8[0][m], cv, sv);
        a8[1][m] = cphase(a8[1][m], cv, sv);
      }
      ry_lane8_2<1>(a8, r, p1ry[l][0]);     // wire0 (lane)
      ry_loc8_2<4>(a8, p1ry[l][1]);         // wire1
      ry_loc8_2<2>(a8, p1ry[l][2]);         // wire2
      ry_loc8_2<1>(a8, p1ry[l][3]);         // wire3
    }

    #pragma unroll
    for (int st = 0; st < 2; ++st){
      float pr8[8];
      #pragma unroll
      for (int m = 0; m < 8; ++m) pr8[m] = a8[st][m].x*a8[st][m].x + a8[st][m].y*a8[st][m].y;
      float s_loc = 0.f;
      #pragma unroll
      for (int m = 0; m < 8; ++m) s_loc += pr8[m];
      float e1 = 0.f, e2 = 0.f, e3 = 0.f;
      #pragma unroll
      for (int m = 0; m < 8; ++m){
        e1 += (m & 4) ? -pr8[m] : pr8[m];
        e2 += (m & 2) ? -pr8[m] : pr8[m];
        e3 += (m & 1) ? -pr8[m] : pr8[m];
      }
      float v0 = Lb ? -s_loc : s_loc;
      v0 += shfx<1>(v0); e1 += shfx<1>(e1); e2 += shfx<1>(e2); e3 += shfx<1>(e3);
      feats[2*g + st][p*4 + 2*Lb + 0] = Lb ? e2 : v0;
      feats[2*g + st][p*4 + 2*Lb + 1] = Lb ? e3 : e1;
    }
    if (r < 16){ feats[2*g][64 + r] = 0.f; feats[2*g + 1][64 + r] = 0.f; }
  }
  __syncthreads();

  // -------- phase-2 chains: 128 distinct jobs on waves 0-3 -----------------
  if (t < 128){
    const int s_ = t >> 3, c = t & 7;
    f32x2 v[2];
    build_psi<9>(v, &feats[s_][c*9], PI_F);
    chain2[s_][c] = {v[0].x, v[0].y, v[1].x, v[1].y};
  }
  __syncthreads();

  // ------- assemble product states: lanes = wires 0-4, local = wires 5-7 ---
  f32x2 a[2][8];
  #pragma unroll
  for (int st = 0; st < 2; ++st){
    const float2* c2 = (const float2*)&chain2[2*g + st][0];
    f32x2 e0 = tov(c2[0*2 + ((r>>4)&1)]);
    f32x2 e1 = tov(c2[1*2 + ((r>>3)&1)]);
    f32x2 e2 = tov(c2[2*2 + ((r>>2)&1)]);
    f32x2 e3 = tov(c2[3*2 + ((r>>1)&1)]);
    f32x2 e4 = tov(c2[4*2 + ( r    &1)]);
    f32x2 L  = cmulv(cmulv(cmulv(e0, e1), cmulv(e2, e3)), e4);

    float4 q5 = chain2[2*g + st][5], q6 = chain2[2*g + st][6], q7 = chain2[2*g + st][7];
    f32x2 p5[2], p6[2], p7[2];
    p5[0].x=q5.x; p5[0].y=q5.y; p5[1].x=q5.z; p5[1].y=q5.w;
    p6[0].x=q6.x; p6[0].y=q6.y; p6[1].x=q6.z; p6[1].y=q6.w;
    p7[0].x=q7.x; p7[0].y=q7.y; p7[1].x=q7.z; p7[1].y=q7.w;
    f32x2 p56[4];
    #pragma unroll
    for (int j = 0; j < 4; ++j) p56[j] = cmulv(p5[j>>1], p6[j&1]);
    f32x2 Lp[4];
    #pragma unroll
    for (int j = 0; j < 4; ++j) Lp[j] = cmulv(L, p56[j]);
    #pragma unroll
    for (int m = 0; m < 8; ++m) a[st][m] = cmulv(Lp[m>>1], p7[m&1]);
  }

  // ---------------- 3 layers: table-CRZ ring + RY on wires 0..7 ------------
  #pragma unroll
  for (int l = 0; l < 3; ++l){
    const float4* ph = &phi2[(l*32 + r)*9];
    #pragma unroll
    for (int m = 0; m < 8; ++m){
      float4 w = ph[m];
      f32x2 cv; cv.x = w.x; cv.y = w.y;
      f32x2 sv; sv.x = w.z; sv.y = w.w;
      a[0][m] = cphase(a[0][m], cv, sv);
      a[1][m] = cphase(a[1][m], cv, sv);
    }
    ry_lane8_2<16>(a, r, ryw[l][0]);        // wire0
    ry_lane8_2<8>(a, r, ryw[l][1]);         // wire1
    ry_lane8_2<4>(a, r, ryw[l][2]);         // wire2
    ry_lane8_2<2>(a, r, ryw[l][3]);         // wire3
    ry_lane8_2<1>(a, r, ryw[l][4]);         // wire4
    ry_loc8_2<4>(a, ryw[l][5]);             // wire5
    ry_loc8_2<2>(a, ryw[l][6]);             // wire6
    ry_loc8_2<1>(a, ryw[l][7]);             // wire7
  }

  // ---------------- measurement + FC (both samples) ------------------------
  float oo[2][3];
  #pragma unroll
  for (int st = 0; st < 2; ++st){
    float pr8[8];
    #pragma unroll
    for (int m = 0; m < 8; ++m) pr8[m] = a[st][m].x*a[st][m].x + a[st][m].y*a[st][m].y;
    float s_loc = 0.f;
    #pragma unroll
    for (int m = 0; m < 8; ++m) s_loc += pr8[m];
    float e5 = 0.f, e6 = 0.f, e7 = 0.f;
    #pragma unroll
    for (int m = 0; m < 8; ++m){
      e5 += (m & 4) ? -pr8[m] : pr8[m];
      e6 += (m & 2) ? -pr8[m] : pr8[m];
      e7 += (m & 1) ? -pr8[m] : pr8[m];
    }
    float gp[8];
    gp[0] = (r & 16) ? -s_loc : s_loc;
    gp[1] = (r &  8) ? -s_loc : s_loc;
    gp[2] = (r &  4) ? -s_loc : s_loc;
    gp[3] = (r &  2) ? -s_loc : s_loc;
    gp[4] = (r &  1) ? -s_loc : s_loc;
    gp[5] = e5; gp[6] = e6; gp[7] = e7;

    float o0 = 0.f, o1 = 0.f, o2 = 0.f;
    #pragma unroll
    for (int w = 0; w < 8; ++w){
      o0 += fcw[0*8 + w] * gp[w];
      o1 += fcw[1*8 + w] * gp[w];
      o2 += fcw[2*8 + w] * gp[w];
    }
    oo[st][0] = o0; oo[st][1] = o1; oo[st][2] = o2;
  }
  #pragma unroll
  for (int k = 0; k < 3; ++k){
    float vA = oo[0][k], vB = oo[1][k];
    vA += shfx<1>(vA);  vB += shfx<1>(vB);
    vA += shfx<2>(vA);  vB += shfx<2>(vB);
    vA += shfx<4>(vA);  vB += shfx<4>(vB);
    vA += shfx<8>(vA);  vB += shfx<8>(vB);
    vA += shfx<16>(vA); vB += shfx<16>(vB);
    oo[0][k] = vA; oo[1][k] = vB;
  }
  if (r < 3){
    out[(size_t)sA*3 + r] = oo[0][r] + fcb[r];
  } else if (r >= 4 && r < 7){
    const int k = r - 4;
    out[(size_t)sB*3 + k] = oo[1][k] + fcb[k];
  }
}

extern "C" void kernel_launch(void* const* d_in, const int* in_sizes, int n_in,
                              void* d_out, int out_size, void* d_ws, size_t ws_size,
                              hipStream_t stream)
{
  const float* X   = (const float*)d_in[0];
  const float* w1  = (const float*)d_in[1];
  const float* w2  = (const float*)d_in[2];
  const float* fcw = (const float*)d_in[3];
  const float* fcb = (const float*)d_in[4];
  float* out = (float*)d_out;
  const int bs = in_sizes[0] / 196;            // 8192
  const int blocks = (bs + 15) / 16;           // 16 samples / 256-thread block
  hipLaunchKernelGGL(qnn_fused_kernel, dim3(blocks), dim3(256), 0, stream,
                     X, w1, w2, fcw, fcb, out, bs);
}